// Round 7
// baseline (237.895 us; speedup 1.0000x reference)
//
#include <hip/hip_runtime.h>

typedef short bf16x8 __attribute__((ext_vector_type(8)));
typedef float f32x4 __attribute__((ext_vector_type(4)));
typedef float f32x16 __attribute__((ext_vector_type(16)));
typedef unsigned short u16;
typedef unsigned short u16x8 __attribute__((ext_vector_type(8)));
typedef unsigned int u32;
typedef unsigned int u32x4 __attribute__((ext_vector_type(4)));

#define MFMA16(a, b, c) __builtin_amdgcn_mfma_f32_16x16x32_bf16((a), (b), (c), 0, 0, 0)
#define MFMA32(a, b, c) __builtin_amdgcn_mfma_f32_32x32x16_bf16((a), (b), (c), 0, 0, 0)

__device__ __forceinline__ u16 f2bf(float f) {
  unsigned u = __builtin_bit_cast(unsigned, f);
  return (u16)((u + 0x7fffu + ((u >> 16) & 1u)) >> 16);
}

__device__ __forceinline__ unsigned cvt_pk_bf16(float lo, float hi) {
  unsigned r;
  asm("v_cvt_pk_bf16_f32 %0, %1, %2" : "=v"(r) : "v"(lo), "v"(hi));
  return r;
}

__device__ __forceinline__ void gload_lds16(const u16* g, u16* lds) {
  __builtin_amdgcn_global_load_lds((__attribute__((address_space(1))) void*)g,
                                   (__attribute__((address_space(3))) void*)lds,
                                   16, 0, 0);
}

// Publish LDS writes + block barrier WITHOUT draining vmcnt (prefetched
// global loads stay in flight across the barrier).
__device__ __forceinline__ void publish_barrier() {
  asm volatile("s_waitcnt lgkmcnt(0)" ::: "memory");
  __builtin_amdgcn_sched_barrier(0);
  __builtin_amdgcn_s_barrier();
}

// ---------------- fp32 -> bf16 conversion (x + 4 weight mats) ----------------
__global__ __launch_bounds__(256) void cvt_all(
    const float* __restrict__ x, const float* __restrict__ w0,
    const float* __restrict__ w1, const float* __restrict__ w2,
    const float* __restrict__ w3, u16* __restrict__ xb, u16* __restrict__ wb) {
  long i = (long)(blockIdx.x * 256 + threadIdx.x) * 8;
  const float* src; u16* dst; long off;
  if (i < 4194304) { src = x; dst = xb; off = i; }
  else {
    long k = i - 4194304; int w = (int)(k >> 20); off = k & 1048575;
    src = (w == 0) ? w0 : (w == 1) ? w1 : (w == 2) ? w2 : w3;
    dst = wb + (long)w * 1048576;
  }
  float4 a = *(const float4*)(src + off);
  float4 b = *(const float4*)(src + off + 4);
  u16x8 o;
  o[0] = f2bf(a.x); o[1] = f2bf(a.y); o[2] = f2bf(a.z); o[3] = f2bf(a.w);
  o[4] = f2bf(b.x); o[5] = f2bf(b.y); o[6] = f2bf(b.z); o[7] = f2bf(b.w);
  *(u16x8*)(dst + off) = o;
}

// ---------------- GEMM  C[M,N] = A[M,K] * B[N,K]^T  (bf16 in, fp32 acc) -----
template <int MODE>
__global__ __launch_bounds__(256) void gemm_bt(
    const u16* __restrict__ A, const u16* __restrict__ Bw,
    u16* __restrict__ Co, float* __restrict__ Cf, const float* __restrict__ bias) {
  constexpr int K = 1024;
  __shared__ u16 As[128 * 32];
  __shared__ u16 Bs[128 * 32];
  const int tid = threadIdx.x, w = tid >> 6, l = tid & 63;
  const int lg = l >> 4, lr = l & 15;
  const int mb = blockIdx.x;
  int mat, nb;
  if (MODE == 0) { mat = blockIdx.y >> 3; nb = blockIdx.y & 7; }
  else           { mat = 0;               nb = blockIdx.y;     }
  const u16* __restrict__ Bp = Bw + (long)mat * 1048576;
  const int wr = w >> 1, wc = w & 1;
  f32x4 acc[4][4] = {};
  const int srow = (l >> 2), scol = (l & 3) * 8;
  for (int kt = 0; kt < K / 32; ++kt) {
    const int kb = kt * 32;
    __syncthreads();
#pragma unroll
    for (int i = 0; i < 2; ++i) {
      int r = w * 32 + i * 16 + srow;
      gload_lds16(A  + (long)(mb * 128 + r) * K + kb + scol, &As[(w * 2 + i) * 512]);
      gload_lds16(Bp + (long)(nb * 128 + r) * K + kb + scol, &Bs[(w * 2 + i) * 512]);
    }
    __syncthreads();
    bf16x8 af[4], bf[4];
#pragma unroll
    for (int m = 0; m < 4; ++m) af[m] = *(const bf16x8*)&As[(wr * 64 + m * 16 + lr) * 32 + lg * 8];
#pragma unroll
    for (int n = 0; n < 4; ++n) bf[n] = *(const bf16x8*)&Bs[(wc * 64 + n * 16 + lr) * 32 + lg * 8];
#pragma unroll
    for (int m = 0; m < 4; ++m)
#pragma unroll
      for (int n = 0; n < 4; ++n)
        acc[m][n] = MFMA16(af[m], bf[n], acc[m][n]);
  }
  const int row0 = mb * 128 + wr * 64, col0 = nb * 128 + wc * 64;
#pragma unroll
  for (int m = 0; m < 4; ++m)
#pragma unroll
    for (int n = 0; n < 4; ++n)
#pragma unroll
      for (int rr = 0; rr < 4; ++rr) {
        int row = row0 + m * 16 + lg * 4 + rr;
        int col = col0 + n * 16 + lr;
        float v = acc[m][n][rr];
        if (MODE == 0) {
          if (mat == 0) v *= 0.18033688011112042f;  // 0.125 * log2(e): softmax in exp2 domain
          Co[(long)mat * 4194304 + (long)row * 1024 + col] = f2bf(v);
        } else {
          Cf[(long)row * 1024 + col] = v + bias[col];
        }
      }
}

// ---------------- flash attention: 32x32 MFMA, in-register P, KV-split -----
// 4 waves = 2 q-tiles x 2 k-halves (static softmax -> partials just sum).
// S^T = mfma32(K, Q): lane holds S[k][q=l&31], k = (reg&3)+8*(reg>>2)+4*(l>>5).
// P->PV B-operand needs k = (l>>5)*8+j per 16-chunk: a single lane^32
// exchange (shfl_xor 32) + cndmask per chunk -- NO LDS roundtrip for P.
// V^T staged swizzled in dbuf LDS (per k-half). K frags JIT from global
// (L2-resident via XCD head clustering). Epilogue combines the two k-halves
// through LDS (aliases the V buffer).
__global__ __launch_bounds__(256, 3) void attn(
    const u16* __restrict__ Qg, const u16* __restrict__ Kg,
    const u16* __restrict__ Vg, u16* __restrict__ Og) {
  __shared__ u16 Vsb[4 * 64 * 72];  // [kh][db][d 64][k-pitch 72]; combine aliases
  const int tid = threadIdx.x, w = tid >> 6, l = tid & 63;
  const int l31 = l & 31, hi = l >> 5;

  // XCD clustering: lin%8 = XCD; 2 heads/XCD -> K+V set 2 MB < 4 MB L2/XCD.
  const int lin = blockIdx.x;
  const int xcd = lin & 7, idx = lin >> 3;
  const int head = xcd * 2 + (idx >> 6), qt = idx & 63;
  const int hb = head * 64;
  const int kh = w >> 1;                 // wave's k-half
  const int q0 = qt * 64 + (w & 1) * 32; // wave's 32 q rows
  const int tb = kh * 32;                // first KV tile of this half

  const u16* __restrict__ Kh = Kg + hb;

  // Q frag (B-operand): Q[q=q0+l31][d = st*16 + hi*8 + j]
  bf16x8 qf[4];
#pragma unroll
  for (int st = 0; st < 4; ++st)
    qf[st] = *(const bf16x8*)&Qg[(long)(q0 + l31) * 1024 + hb + st * 16 + hi * 8];

  f32x16 o0 = {}, o1 = {};  // ctx^T accum: col=q, rows d 0..31 / 32..63
  float sls = 0.f;

  // V staging: thread stages rows (2kr,2kr+1) of BOTH k-half tiles, octet c8
  const int kr = tid >> 3, c8 = tid & 7;
  const u16* Vgp = Vg + hb + c8 * 8;
  bf16x8 va0, va1, vb0, vb1;
  u16* VsA = Vsb;                  // kh=0 dbuf
  u16* VsB = Vsb + 2 * 4608;       // kh=1 dbuf (4608 = 64*72)

#define VLOAD(t_)                                                     \
  {                                                                   \
    long r0_ = (long)(t_) * 64 + kr * 2;                              \
    va0 = *(const bf16x8*)&Vgp[r0_ * 1024];                           \
    va1 = *(const bf16x8*)&Vgp[(r0_ + 1) * 1024];                     \
    vb0 = *(const bf16x8*)&Vgp[(r0_ + 2048) * 1024];                  \
    vb1 = *(const bf16x8*)&Vgp[(r0_ + 2049) * 1024];                  \
  }

#define VWRITE(db_)                                                   \
  {                                                                   \
    const int cw = (kr ^ (c8 << 2)) * 2;                              \
    u16* da_ = VsA + (db_)*4608;                                      \
    u16* db2_ = VsB + (db_)*4608;                                     \
    _Pragma("unroll") for (int j = 0; j < 8; ++j) {                   \
      u32 p0 = (u32)(u16)va0[j] | ((u32)(u16)va1[j] << 16);           \
      u32 p1 = (u32)(u16)vb0[j] | ((u32)(u16)vb1[j] << 16);           \
      *(u32*)&da_[(c8 * 8 + j) * 72 + cw] = p0;                       \
      *(u32*)&db2_[(c8 * 8 + j) * 72 + cw] = p1;                      \
    }                                                                 \
  }

  VLOAD(0);
  VWRITE(0);
  publish_barrier();

  for (int t = 0; t < 32; ++t) {
    const int db = t & 1;
    if (t < 31) VLOAD(t + 1);  // T14: issue next V loads under compute

    // K frags JIT (A-operand): K[k=(tb+t)*64 + tt*32 + l31][st*16+hi*8+j]
    bf16x8 ka[2][4];
#pragma unroll
    for (int tt = 0; tt < 2; ++tt)
#pragma unroll
      for (int st = 0; st < 4; ++st)
        ka[tt][st] = *(const bf16x8*)
            &Kh[(long)((tb + t) * 64 + tt * 32 + l31) * 1024 + st * 16 + hi * 8];

    f32x16 S0 = {}, S1 = {};
    __builtin_amdgcn_s_setprio(1);
#pragma unroll
    for (int st = 0; st < 4; ++st) {
      S0 = MFMA32(ka[0][st], qf[st], S0);
      S1 = MFMA32(ka[1][st], qf[st], S1);
    }
    __builtin_amdgcn_s_setprio(0);

    // static softmax: exp2 everything (scale folded upstream), accumulate ls
#pragma unroll
    for (int r = 0; r < 16; ++r) {
      S0[r] = __builtin_amdgcn_exp2f(S0[r]);
      S1[r] = __builtin_amdgcn_exp2f(S1[r]);
      sls += S0[r] + S1[r];
    }

    // per 16-k chunk: pack to bf16, lane^32 exchange -> PV B-frag; then MFMA
    const u16* myV = Vsb + kh * 2 * 4608 + db * 4608;
#pragma unroll
    for (int c = 0; c < 4; ++c) {
      const int cc = c & 1;
      u32 A0, A1, B0, B1;
      if (c < 2) {
        A0 = cvt_pk_bf16(S0[(2 * cc) * 4 + 0], S0[(2 * cc) * 4 + 1]);
        A1 = cvt_pk_bf16(S0[(2 * cc) * 4 + 2], S0[(2 * cc) * 4 + 3]);
        B0 = cvt_pk_bf16(S0[(2 * cc + 1) * 4 + 0], S0[(2 * cc + 1) * 4 + 1]);
        B1 = cvt_pk_bf16(S0[(2 * cc + 1) * 4 + 2], S0[(2 * cc + 1) * 4 + 3]);
      } else {
        A0 = cvt_pk_bf16(S1[(2 * cc) * 4 + 0], S1[(2 * cc) * 4 + 1]);
        A1 = cvt_pk_bf16(S1[(2 * cc) * 4 + 2], S1[(2 * cc) * 4 + 3]);
        B0 = cvt_pk_bf16(S1[(2 * cc + 1) * 4 + 0], S1[(2 * cc + 1) * 4 + 1]);
        B1 = cvt_pk_bf16(S1[(2 * cc + 1) * 4 + 2], S1[(2 * cc + 1) * 4 + 3]);
      }
      // send partner what it needs: hi=0 sends B*, hi=1 sends A*
      u32 x0 = hi ? A0 : B0, x1 = hi ? A1 : B1;
      u32 r0 = __shfl_xor((int)x0, 32);
      u32 r1 = __shfl_xor((int)x1, 32);
      u32x4 fv;
      fv[0] = hi ? r0 : A0;
      fv[1] = hi ? r1 : A1;
      fv[2] = hi ? B0 : r0;
      fv[3] = hi ? B1 : r1;
      bf16x8 pb = __builtin_bit_cast(bf16x8, fv);
      // V^T frags: row d = dt*32+l31, dword col (8c+4hi) ^ row-swizzle
      const int sw0 = ((8 * c + 4 * hi) ^ (((l31 >> 3) & 7) << 2)) * 2;
      const int sw1 = ((8 * c + 4 * hi) ^ ((((l31 + 32) >> 3) & 7) << 2)) * 2;
      bf16x8 vf0 = *(const bf16x8*)&myV[l31 * 72 + sw0];
      bf16x8 vf1 = *(const bf16x8*)&myV[(32 + l31) * 72 + sw1];
      __builtin_amdgcn_s_setprio(1);
      o0 = MFMA32(vf0, pb, o0);
      o1 = MFMA32(vf1, pb, o1);
      __builtin_amdgcn_s_setprio(0);
    }

    if (t < 31) VWRITE(db ^ 1);  // counted vmcnt wait on staging regs only
    publish_barrier();           // prefetches stay in flight
  }

  // ---- combine k-halves via LDS (aliases Vsb; loop barrier already passed) --
  float* cb = (float*)Vsb;
  if (kh == 1) {
    const int base = (w - 2) * (64 * 33) + l * 33;
#pragma unroll
    for (int r = 0; r < 16; ++r) {
      cb[base + r] = o0[r];
      cb[base + 16 + r] = o1[r];
    }
    cb[base + 32] = sls;
  }
  publish_barrier();
  if (kh == 0) {
    const int base = w * (64 * 33) + l * 33;
#pragma unroll
    for (int r = 0; r < 16; ++r) {
      o0[r] += cb[base + r];
      o1[r] += cb[base + 16 + r];
    }
    sls += cb[base + 32];
    float s = sls + __shfl_xor(sls, 32);
    float inv = 1.0f / s;
#pragma unroll
    for (int dt = 0; dt < 2; ++dt) {
#pragma unroll
      for (int r2 = 0; r2 < 4; ++r2) {
        float v0 = dt ? o1[r2 * 4 + 0] : o0[r2 * 4 + 0];
        float v1 = dt ? o1[r2 * 4 + 1] : o0[r2 * 4 + 1];
        float v2 = dt ? o1[r2 * 4 + 2] : o0[r2 * 4 + 2];
        float v3 = dt ? o1[r2 * 4 + 3] : o0[r2 * 4 + 3];
        uint2 pk;
        pk.x = cvt_pk_bf16(v0 * inv, v1 * inv);
        pk.y = cvt_pk_bf16(v2 * inv, v3 * inv);
        const int d0 = dt * 32 + 8 * r2 + 4 * hi;
        *(uint2*)&Og[(long)(q0 + l31) * 1024 + hb + d0] = pk;
      }
    }
  }
#undef VLOAD
#undef VWRITE
}

extern "C" void kernel_launch(void* const* d_in, const int* in_sizes, int n_in,
                              void* d_out, int out_size, void* d_ws, size_t ws_size,
                              hipStream_t stream) {
  const float* x  = (const float*)d_in[0];
  const float* Wq = (const float*)d_in[1];
  const float* Wk = (const float*)d_in[2];
  const float* Wv = (const float*)d_in[3];
  const float* Wo = (const float*)d_in[4];
  const float* bo = (const float*)d_in[5];
  float* out = (float*)d_out;

  u16* xb  = (u16*)d_ws;            // 4096x1024 bf16
  u16* wb  = xb + 4194304;          // 4 x 1024x1024 bf16 (Wq,Wk,Wv,Wo)
  u16* qkv = wb + 4194304;          // Q,K,V each 4096x1024 bf16
  u16* ctx = qkv + 3 * 4194304;     // 4096x1024 bf16

  cvt_all<<<dim3(4096), dim3(256), 0, stream>>>(x, Wq, Wk, Wv, Wo, xb, wb);
  gemm_bt<0><<<dim3(32, 24), dim3(256), 0, stream>>>(xb, wb, qkv, nullptr, nullptr);
  attn<<<dim3(1024), dim3(256), 0, stream>>>(qkv, qkv + 4194304, qkv + 8388608, ctx);
  gemm_bt<1><<<dim3(32, 8), dim3(256), 0, stream>>>(ctx, wb + 3 * 1048576, nullptr, out, bo);
}

// Round 9
// 194.360 us; speedup vs baseline: 1.2240x; 1.2240x over previous
//
#include <hip/hip_runtime.h>

typedef short bf16x8 __attribute__((ext_vector_type(8)));
typedef float f32x4 __attribute__((ext_vector_type(4)));
typedef float f32x16 __attribute__((ext_vector_type(16)));
typedef unsigned short u16;
typedef unsigned short u16x8 __attribute__((ext_vector_type(8)));
typedef unsigned int u32;
typedef unsigned int u32x4 __attribute__((ext_vector_type(4)));

#define MFMA16(a, b, c) __builtin_amdgcn_mfma_f32_16x16x32_bf16((a), (b), (c), 0, 0, 0)
#define MFMA32(a, b, c) __builtin_amdgcn_mfma_f32_32x32x16_bf16((a), (b), (c), 0, 0, 0)

__device__ __forceinline__ u16 f2bf(float f) {
  unsigned u = __builtin_bit_cast(unsigned, f);
  return (u16)((u + 0x7fffu + ((u >> 16) & 1u)) >> 16);
}

__device__ __forceinline__ unsigned cvt_pk_bf16(float lo, float hi) {
  unsigned r;
  asm("v_cvt_pk_bf16_f32 %0, %1, %2" : "=v"(r) : "v"(lo), "v"(hi));
  return r;
}

__device__ __forceinline__ void gload_lds16(const u16* g, u16* lds) {
  __builtin_amdgcn_global_load_lds((__attribute__((address_space(1))) void*)g,
                                   (__attribute__((address_space(3))) void*)lds,
                                   16, 0, 0);
}

// Publish LDS writes + block barrier WITHOUT draining vmcnt (prefetched
// global loads stay in flight across the barrier).
__device__ __forceinline__ void publish_barrier() {
  asm volatile("s_waitcnt lgkmcnt(0)" ::: "memory");
  __builtin_amdgcn_sched_barrier(0);
  __builtin_amdgcn_s_barrier();
}

// ---------------- fp32 -> bf16 conversion (x + 4 weight mats) ----------------
__global__ __launch_bounds__(256) void cvt_all(
    const float* __restrict__ x, const float* __restrict__ w0,
    const float* __restrict__ w1, const float* __restrict__ w2,
    const float* __restrict__ w3, u16* __restrict__ xb, u16* __restrict__ wb) {
  long i = (long)(blockIdx.x * 256 + threadIdx.x) * 8;
  const float* src; u16* dst; long off;
  if (i < 4194304) { src = x; dst = xb; off = i; }
  else {
    long k = i - 4194304; int w = (int)(k >> 20); off = k & 1048575;
    src = (w == 0) ? w0 : (w == 1) ? w1 : (w == 2) ? w2 : w3;
    dst = wb + (long)w * 1048576;
  }
  float4 a = *(const float4*)(src + off);
  float4 b = *(const float4*)(src + off + 4);
  u16x8 o;
  o[0] = f2bf(a.x); o[1] = f2bf(a.y); o[2] = f2bf(a.z); o[3] = f2bf(a.w);
  o[4] = f2bf(b.x); o[5] = f2bf(b.y); o[6] = f2bf(b.z); o[7] = f2bf(b.w);
  *(u16x8*)(dst + off) = o;
}

// ---------------- GEMM  C[M,N] = A[M,K] * B[N,K]^T  (bf16 in, fp32 acc) -----
template <int MODE>
__global__ __launch_bounds__(256) void gemm_bt(
    const u16* __restrict__ A, const u16* __restrict__ Bw,
    u16* __restrict__ Co, float* __restrict__ Cf, const float* __restrict__ bias) {
  constexpr int K = 1024;
  __shared__ u16 As[128 * 32];
  __shared__ u16 Bs[128 * 32];
  const int tid = threadIdx.x, w = tid >> 6, l = tid & 63;
  const int lg = l >> 4, lr = l & 15;
  const int mb = blockIdx.x;
  int mat, nb;
  if (MODE == 0) { mat = blockIdx.y >> 3; nb = blockIdx.y & 7; }
  else           { mat = 0;               nb = blockIdx.y;     }
  const u16* __restrict__ Bp = Bw + (long)mat * 1048576;
  const int wr = w >> 1, wc = w & 1;
  f32x4 acc[4][4] = {};
  const int srow = (l >> 2), scol = (l & 3) * 8;
  for (int kt = 0; kt < K / 32; ++kt) {
    const int kb = kt * 32;
    __syncthreads();
#pragma unroll
    for (int i = 0; i < 2; ++i) {
      int r = w * 32 + i * 16 + srow;
      gload_lds16(A  + (long)(mb * 128 + r) * K + kb + scol, &As[(w * 2 + i) * 512]);
      gload_lds16(Bp + (long)(nb * 128 + r) * K + kb + scol, &Bs[(w * 2 + i) * 512]);
    }
    __syncthreads();
    bf16x8 af[4], bf[4];
#pragma unroll
    for (int m = 0; m < 4; ++m) af[m] = *(const bf16x8*)&As[(wr * 64 + m * 16 + lr) * 32 + lg * 8];
#pragma unroll
    for (int n = 0; n < 4; ++n) bf[n] = *(const bf16x8*)&Bs[(wc * 64 + n * 16 + lr) * 32 + lg * 8];
#pragma unroll
    for (int m = 0; m < 4; ++m)
#pragma unroll
      for (int n = 0; n < 4; ++n)
        acc[m][n] = MFMA16(af[m], bf[n], acc[m][n]);
  }
  const int row0 = mb * 128 + wr * 64, col0 = nb * 128 + wc * 64;
#pragma unroll
  for (int m = 0; m < 4; ++m)
#pragma unroll
    for (int n = 0; n < 4; ++n)
#pragma unroll
      for (int rr = 0; rr < 4; ++rr) {
        int row = row0 + m * 16 + lg * 4 + rr;
        int col = col0 + n * 16 + lr;
        float v = acc[m][n][rr];
        if (MODE == 0) {
          if (mat == 0) v *= 0.18033688011112042f;  // 0.125 * log2(e): softmax in exp2 domain
          Co[(long)mat * 4194304 + (long)row * 1024 + col] = f2bf(v);
        } else {
          Cf[(long)row * 1024 + col] = v + bias[col];
        }
      }
}

// ---------------- flash attention: 32x32 MFMA, in-reg P, pipelined K -------
// 4 waves = 4 q-tiles of 32 rows; full k sweep (64 iters of 64 k).
// S^T = mfma32(K, Q): lane holds S[k][q=l&31], k = (reg&3)+8*(reg>>2)+4*(l>>5).
// P -> PV B-operand via ONE shfl_xor(32) exchange per reg pair (no P LDS).
// K frags from global (L2-resident via XCD head clustering), prefetched
// IN-PLACE for t+1 right after QK^T(t) consumes them (WAR safe: MFMA reads
// at issue). V^T swizzled in dbuf LDS; single counted-wait barrier per iter.
__global__ __launch_bounds__(256, 2) void attn(
    const u16* __restrict__ Qg, const u16* __restrict__ Kg,
    const u16* __restrict__ Vg, u16* __restrict__ Og) {
  __shared__ u16 Vsb[2 * 64 * 72];  // dbuf V^T [d 64][k-pitch 72], swizzled
  const int tid = threadIdx.x, w = tid >> 6, l = tid & 63;
  const int l31 = l & 31, hi = l >> 5;

  // XCD clustering: lin%8 = XCD; 2 heads/XCD -> K+V set 2 MB < 4 MB L2/XCD.
  const int lin = blockIdx.x;
  const int xcd = lin & 7, idx = lin >> 3;
  const int head = xcd * 2 + (idx >> 5), qt = idx & 31;
  const int hb = head * 64;
  const int q0 = qt * 128 + w * 32;

  const u16* __restrict__ Kh = Kg + hb;

  // Q frag (B-operand): Q[q=q0+l31][d = st*16 + hi*8 + j]
  bf16x8 qf[4];
#pragma unroll
  for (int st = 0; st < 4; ++st)
    qf[st] = *(const bf16x8*)&Qg[(long)(q0 + l31) * 1024 + hb + st * 16 + hi * 8];

  f32x16 o0 = {}, o1 = {};  // ctx^T accum: col=q, rows d 0..31 / 32..63
  f32x4 lsv = {};

  // V staging: thread stages rows (2kr, 2kr+1), octet c8
  const int kr = tid >> 3, c8 = tid & 7;
  const u16* Vgp = Vg + hb + c8 * 8;
  bf16x8 va0, va1;
  bf16x8 ka[2][4];

#define VLOAD(t_)                                                     \
  {                                                                   \
    long r0_ = (long)(t_) * 64 + kr * 2;                              \
    va0 = *(const bf16x8*)&Vgp[r0_ * 1024];                           \
    va1 = *(const bf16x8*)&Vgp[(r0_ + 1) * 1024];                     \
  }

#define VWRITE(db_)                                                   \
  {                                                                   \
    const int cw = (kr ^ (c8 << 2)) * 2;                              \
    u16* d_ = Vsb + (db_) * 4608;                                     \
    _Pragma("unroll") for (int j = 0; j < 8; ++j) {                   \
      u32 p0 = (u32)(u16)va0[j] | ((u32)(u16)va1[j] << 16);           \
      *(u32*)&d_[(c8 * 8 + j) * 72 + cw] = p0;                        \
    }                                                                 \
  }

#define KLOAD(t_)                                                             \
  {                                                                           \
    _Pragma("unroll") for (int tt = 0; tt < 2; ++tt)                          \
      _Pragma("unroll") for (int st = 0; st < 4; ++st)                        \
        ka[tt][st] = *(const bf16x8*)                                         \
            &Kh[(long)((t_) * 64 + tt * 32 + l31) * 1024 + st * 16 + hi * 8]; \
  }

  // prologue
  VLOAD(0);
  KLOAD(0);
  VWRITE(0);
  publish_barrier();

  for (int t = 0; t < 64; ++t) {
    const int db = t & 1;
    if (t < 63) VLOAD(t + 1);  // T14: issue next V loads under compute

    f32x16 S0 = {}, S1 = {};
    __builtin_amdgcn_s_setprio(1);
#pragma unroll
    for (int st = 0; st < 4; ++st) {
      S0 = MFMA32(ka[0][st], qf[st], S0);
      S1 = MFMA32(ka[1][st], qf[st], S1);
    }
    __builtin_amdgcn_s_setprio(0);
    if (t < 63) KLOAD(t + 1);  // in-place K prefetch (WAR safe)

    // static softmax: exp2 everything (scale folded upstream)
#pragma unroll
    for (int r = 0; r < 16; ++r) {
      S0[r] = __builtin_amdgcn_exp2f(S0[r]);
      S1[r] = __builtin_amdgcn_exp2f(S1[r]);
    }

    // per 16-k chunk: pack to bf16, lane^32 exchange -> PV B-frag; then MFMA
    const u16* myV = Vsb + db * 4608;
#pragma unroll
    for (int c = 0; c < 4; ++c) {
      const int cc = c & 1;
      u32 A0, A1, B0, B1;
      if (c < 2) {
        A0 = cvt_pk_bf16(S0[(2 * cc) * 4 + 0], S0[(2 * cc) * 4 + 1]);
        A1 = cvt_pk_bf16(S0[(2 * cc) * 4 + 2], S0[(2 * cc) * 4 + 3]);
        B0 = cvt_pk_bf16(S0[(2 * cc + 1) * 4 + 0], S0[(2 * cc + 1) * 4 + 1]);
        B1 = cvt_pk_bf16(S0[(2 * cc + 1) * 4 + 2], S0[(2 * cc + 1) * 4 + 3]);
      } else {
        A0 = cvt_pk_bf16(S1[(2 * cc) * 4 + 0], S1[(2 * cc) * 4 + 1]);
        A1 = cvt_pk_bf16(S1[(2 * cc) * 4 + 2], S1[(2 * cc) * 4 + 3]);
        B0 = cvt_pk_bf16(S1[(2 * cc + 1) * 4 + 0], S1[(2 * cc + 1) * 4 + 1]);
        B1 = cvt_pk_bf16(S1[(2 * cc + 1) * 4 + 2], S1[(2 * cc + 1) * 4 + 3]);
      }
      // send partner what it needs: hi=0 sends B*, hi=1 sends A*
      u32 x0 = hi ? A0 : B0, x1 = hi ? A1 : B1;
      u32 r0 = __shfl_xor((int)x0, 32);
      u32 r1 = __shfl_xor((int)x1, 32);
      u32x4 fv;
      fv[0] = hi ? r0 : A0;
      fv[1] = hi ? r1 : A1;
      fv[2] = hi ? B0 : r0;
      fv[3] = hi ? B1 : r1;
      bf16x8 pb = __builtin_bit_cast(bf16x8, fv);
      // V^T frags: row d = dt*32+l31, dword col (8c+4hi) ^ row-swizzle
      const int sw0 = ((8 * c + 4 * hi) ^ (((l31 >> 3) & 7) << 2)) * 2;
      const int sw1 = ((8 * c + 4 * hi) ^ ((((l31 + 32) >> 3) & 7) << 2)) * 2;
      bf16x8 vf0 = *(const bf16x8*)&myV[l31 * 72 + sw0];
      bf16x8 vf1 = *(const bf16x8*)&myV[(32 + l31) * 72 + sw1];
      __builtin_amdgcn_s_setprio(1);
      o0 = MFMA32(vf0, pb, o0);
      o1 = MFMA32(vf1, pb, o1);
      __builtin_amdgcn_s_setprio(0);
    }

    // ls partials (off the critical path, 4 independent add chains)
#pragma unroll
    for (int r2 = 0; r2 < 4; ++r2)
#pragma unroll
      for (int j = 0; j < 4; ++j)
        lsv[j] += S0[r2 * 4 + j] + S1[r2 * 4 + j];

    if (t < 63) VWRITE(db ^ 1);  // counted vmcnt wait on staging regs only
    publish_barrier();           // prefetches stay in flight
  }

  // epilogue: reduce ls over both k-half lanes, normalize, store ctx^T
  {
    float sls = (lsv[0] + lsv[1]) + (lsv[2] + lsv[3]);
    float s = sls + __shfl_xor(sls, 32);
    float inv = 1.0f / s;
#pragma unroll
    for (int dt = 0; dt < 2; ++dt) {
#pragma unroll
      for (int r2 = 0; r2 < 4; ++r2) {
        float v0 = dt ? o1[r2 * 4 + 0] : o0[r2 * 4 + 0];
        float v1 = dt ? o1[r2 * 4 + 1] : o0[r2 * 4 + 1];
        float v2 = dt ? o1[r2 * 4 + 2] : o0[r2 * 4 + 2];
        float v3 = dt ? o1[r2 * 4 + 3] : o0[r2 * 4 + 3];
        uint2 pk;
        pk.x = cvt_pk_bf16(v0 * inv, v1 * inv);
        pk.y = cvt_pk_bf16(v2 * inv, v3 * inv);
        const int d0 = dt * 32 + 8 * r2 + 4 * hi;
        *(uint2*)&Og[(long)(q0 + l31) * 1024 + hb + d0] = pk;
      }
    }
  }
#undef VLOAD
#undef VWRITE
#undef KLOAD
}

extern "C" void kernel_launch(void* const* d_in, const int* in_sizes, int n_in,
                              void* d_out, int out_size, void* d_ws, size_t ws_size,
                              hipStream_t stream) {
  const float* x  = (const float*)d_in[0];
  const float* Wq = (const float*)d_in[1];
  const float* Wk = (const float*)d_in[2];
  const float* Wv = (const float*)d_in[3];
  const float* Wo = (const float*)d_in[4];
  const float* bo = (const float*)d_in[5];
  float* out = (float*)d_out;

  u16* xb  = (u16*)d_ws;            // 4096x1024 bf16
  u16* wb  = xb + 4194304;          // 4 x 1024x1024 bf16 (Wq,Wk,Wv,Wo)
  u16* qkv = wb + 4194304;          // Q,K,V each 4096x1024 bf16
  u16* ctx = qkv + 3 * 4194304;     // 4096x1024 bf16

  cvt_all<<<dim3(4096), dim3(256), 0, stream>>>(x, Wq, Wk, Wv, Wo, xb, wb);
  gemm_bt<0><<<dim3(32, 24), dim3(256), 0, stream>>>(xb, wb, qkv, nullptr, nullptr);
  attn<<<dim3(512), dim3(256), 0, stream>>>(qkv, qkv + 4194304, qkv + 8388608, ctx);
  gemm_bt<1><<<dim3(32, 8), dim3(256), 0, stream>>>(ctx, wb + 3 * 1048576, nullptr, out, bo);
}